// Round 1
// baseline (680.228 us; speedup 1.0000x reference)
//
#include <hip/hip_runtime.h>
#include <math.h>

#define N_TOK 8192
#define DMODEL 1024
#define DHEAD 128
#define NM (N_TOK * DHEAD)  // 1048576 floats per projection

static __device__ __forceinline__ float4 ld4(const float* p) {
    return *(const float4*)p;
}

// ---------------------------------------------------------------------------
// K1: projections  P = X @ W  for W in {Wq, Wk, Wv}
// grid (128, 3), block 256. Tile: 64 rows x 128 cols, K-step 32.
// ---------------------------------------------------------------------------
__global__ __launch_bounds__(256) void proj_kernel(
    const float* __restrict__ X, const float* __restrict__ Wq,
    const float* __restrict__ Wk, const float* __restrict__ Wv,
    float* __restrict__ ws) {
    __shared__ float Xt[32][68];    // transposed: Xt[k][row]
    __shared__ float Wt[32][132];   // row-major:  Wt[k][col]
    const int tid = threadIdx.x;
    const int tx = tid & 15, ty = tid >> 4;
    const int rb = blockIdx.x * 64;
    const float* W = blockIdx.y == 0 ? Wq : (blockIdx.y == 1 ? Wk : Wv);
    float* P = ws + (size_t)blockIdx.y * NM;

    float acc[4][8] = {};
    for (int k0 = 0; k0 < DMODEL; k0 += 32) {
        __syncthreads();
        {   // stage X transposed: 64 rows x 32 k
            int r = tid & 63;
            int kq = (tid >> 6) << 2;  // 0,4,8,12
#pragma unroll
            for (int h = 0; h < 2; ++h) {
                int kk = kq + 16 * h;
                float4 v = ld4(&X[(size_t)(rb + r) * DMODEL + k0 + kk]);
                Xt[kk + 0][r] = v.x; Xt[kk + 1][r] = v.y;
                Xt[kk + 2][r] = v.z; Xt[kk + 3][r] = v.w;
            }
        }
        {   // stage W: 32 rows x 128 cols
            int kk = tid >> 3;
            int c4 = (tid & 7) << 2;
#pragma unroll
            for (int p = 0; p < 4; ++p) {
                float4 v = ld4(&W[(size_t)(k0 + kk) * DHEAD + c4 + 32 * p]);
                *(float4*)&Wt[kk][c4 + 32 * p] = v;
            }
        }
        __syncthreads();
#pragma unroll 8
        for (int kk = 0; kk < 32; ++kk) {
            float4 a  = ld4(&Xt[kk][ty << 2]);
            float4 b0 = ld4(&Wt[kk][tx << 2]);
            float4 b1 = ld4(&Wt[kk][64 + (tx << 2)]);
            float av[4] = {a.x, a.y, a.z, a.w};
            float bv[8] = {b0.x, b0.y, b0.z, b0.w, b1.x, b1.y, b1.z, b1.w};
#pragma unroll
            for (int i = 0; i < 4; ++i)
#pragma unroll
                for (int j = 0; j < 8; ++j)
                    acc[i][j] = fmaf(av[i], bv[j], acc[i][j]);
        }
    }
#pragma unroll
    for (int i = 0; i < 4; ++i) {
        size_t row = rb + (ty << 2) + i;
        float4 o0 = {acc[i][0], acc[i][1], acc[i][2], acc[i][3]};
        float4 o1 = {acc[i][4], acc[i][5], acc[i][6], acc[i][7]};
        *(float4*)&P[row * DHEAD + (tx << 2)] = o0;
        *(float4*)&P[row * DHEAD + 64 + (tx << 2)] = o1;
    }
}

// ---------------------------------------------------------------------------
// K2: scores S = Q K^T * scale -> attn (raw), plus online per-row (m, l)
// grid (128 row-blocks, 4 col-splits), block 256. 64 rows x 2048 cols/block.
// ---------------------------------------------------------------------------
__global__ __launch_bounds__(256) void scores_kernel(
    const float* __restrict__ ws_qk, float* __restrict__ attn,
    float* __restrict__ mpart, float* __restrict__ lpart) {
    __shared__ float Qt[128][68];   // Qt[d][row]
    __shared__ float Kt[128][68];   // Kt[d][col]
    const float* Q  = ws_qk;
    const float* Kp = ws_qk + NM;
    const int tid = threadIdx.x;
    const int tx = tid & 15, ty = tid >> 4;
    const int rb = blockIdx.x * 64;
    const int c_begin = blockIdx.y * 2048;
    const float scale = 0.08838834764831845f;  // 1/sqrt(128)

    {   // load Q block transposed (once)
        int r = tid & 63;
#pragma unroll
        for (int h = 0; h < 8; ++h) {
            int d4 = (((tid >> 6) + (h << 2))) << 2;  // 0..124 step 4
            float4 v = ld4(&Q[(size_t)(rb + r) * DHEAD + d4]);
            Qt[d4 + 0][r] = v.x; Qt[d4 + 1][r] = v.y;
            Qt[d4 + 2][r] = v.z; Qt[d4 + 3][r] = v.w;
        }
    }
    float m[4], l[4];
#pragma unroll
    for (int i = 0; i < 4; ++i) { m[i] = -INFINITY; l[i] = 0.f; }

    for (int ct = 0; ct < 32; ++ct) {
        const int cb = c_begin + ct * 64;
        __syncthreads();
        {   // stage K tile transposed
            int c = tid & 63;
#pragma unroll
            for (int h = 0; h < 8; ++h) {
                int d4 = (((tid >> 6) + (h << 2))) << 2;
                float4 v = ld4(&Kp[(size_t)(cb + c) * DHEAD + d4]);
                Kt[d4 + 0][c] = v.x; Kt[d4 + 1][c] = v.y;
                Kt[d4 + 2][c] = v.z; Kt[d4 + 3][c] = v.w;
            }
        }
        __syncthreads();
        float s[4][4] = {};
#pragma unroll 16
        for (int d = 0; d < 128; ++d) {
            float4 a = ld4(&Qt[d][ty << 2]);
            float4 b = ld4(&Kt[d][tx << 2]);
            float av[4] = {a.x, a.y, a.z, a.w};
            float bv[4] = {b.x, b.y, b.z, b.w};
#pragma unroll
            for (int i = 0; i < 4; ++i)
#pragma unroll
                for (int j = 0; j < 4; ++j)
                    s[i][j] = fmaf(av[i], bv[j], s[i][j]);
        }
#pragma unroll
        for (int i = 0; i < 4; ++i) {
            float4 sv;
            sv.x = s[i][0] * scale; sv.y = s[i][1] * scale;
            sv.z = s[i][2] * scale; sv.w = s[i][3] * scale;
            size_t row = rb + (ty << 2) + i;
            *(float4*)&attn[row * (size_t)N_TOK + cb + (tx << 2)] = sv;
            float tm = fmaxf(fmaxf(sv.x, sv.y), fmaxf(sv.z, sv.w));
#pragma unroll
            for (int o = 1; o < 16; o <<= 1) tm = fmaxf(tm, __shfl_xor(tm, o));
            float mn = fmaxf(m[i], tm);
            float ps = expf(sv.x - mn) + expf(sv.y - mn) +
                       expf(sv.z - mn) + expf(sv.w - mn);
#pragma unroll
            for (int o = 1; o < 16; o <<= 1) ps += __shfl_xor(ps, o);
            l[i] = l[i] * expf(m[i] - mn) + ps;
            m[i] = mn;
        }
    }
    if (tx == 0) {
#pragma unroll
        for (int i = 0; i < 4; ++i) {
            int row = rb + (ty << 2) + i;
            mpart[blockIdx.y * N_TOK + row] = m[i];
            lpart[blockIdx.y * N_TOK + row] = l[i];
        }
    }
}

// ---------------------------------------------------------------------------
// K2b: merge 4 column-split (m,l) partials; store m and 1/l
// ---------------------------------------------------------------------------
__global__ __launch_bounds__(256) void merge_kernel(
    const float* __restrict__ mpart, const float* __restrict__ lpart,
    float* __restrict__ mfin, float* __restrict__ lrin) {
    int row = blockIdx.x * 256 + threadIdx.x;
    float m = mpart[row];
#pragma unroll
    for (int c = 1; c < 4; ++c) m = fmaxf(m, mpart[c * N_TOK + row]);
    float l = 0.f;
#pragma unroll
    for (int c = 0; c < 4; ++c)
        l += lpart[c * N_TOK + row] * expf(mpart[c * N_TOK + row] - m);
    mfin[row] = m;
    lrin[row] = 1.0f / l;
}

// ---------------------------------------------------------------------------
// K3: normalize attention in place + partial O = P @ V per column split
// grid (128, 4), block 256. 64 rows x 2048 cols per block.
// ---------------------------------------------------------------------------
__global__ __launch_bounds__(256) void pv_kernel(
    const float* __restrict__ Vp, const float* __restrict__ mfin,
    const float* __restrict__ lrin, float* __restrict__ attn,
    float* __restrict__ opart) {
    __shared__ float Ps[64][68];    // Ps[row][col]
    __shared__ float Vs[64][132];   // Vs[col][d]
    const int tid = threadIdx.x;
    const int tx = tid & 15, ty = tid >> 4;
    const int rb = blockIdx.x * 64;
    const int c_begin = blockIdx.y * 2048;

    float mreg[4], rreg[4];
#pragma unroll
    for (int i = 0; i < 4; ++i) {
        int row = rb + (ty << 2) + i;
        mreg[i] = mfin[row];
        rreg[i] = lrin[row];
    }
    float acc[4][8] = {};
    for (int ct = 0; ct < 32; ++ct) {
        const int cb = c_begin + ct * 64;
        __syncthreads();
        {   // stage V tile (rows cb..cb+63)
#pragma unroll
            for (int h = 0; h < 8; ++h) {
                int r = (tid >> 5) + (h << 3);
                int d4 = (tid & 31) << 2;
                float4 v = ld4(&Vp[(size_t)(cb + r) * DHEAD + d4]);
                *(float4*)&Vs[r][d4] = v;
            }
        }
        // own raw S -> p, write back + to LDS
#pragma unroll
        for (int i = 0; i < 4; ++i) {
            size_t row = rb + (ty << 2) + i;
            float4 sv = ld4(&attn[row * (size_t)N_TOK + cb + (tx << 2)]);
            float4 p;
            p.x = expf(sv.x - mreg[i]) * rreg[i];
            p.y = expf(sv.y - mreg[i]) * rreg[i];
            p.z = expf(sv.z - mreg[i]) * rreg[i];
            p.w = expf(sv.w - mreg[i]) * rreg[i];
            *(float4*)&attn[row * (size_t)N_TOK + cb + (tx << 2)] = p;
            *(float4*)&Ps[(ty << 2) + i][tx << 2] = p;
        }
        __syncthreads();
#pragma unroll 8
        for (int c = 0; c < 64; ++c) {
            float a0 = Ps[(ty << 2) + 0][c];
            float a1 = Ps[(ty << 2) + 1][c];
            float a2 = Ps[(ty << 2) + 2][c];
            float a3 = Ps[(ty << 2) + 3][c];
            float4 b0 = ld4(&Vs[c][tx << 2]);
            float4 b1 = ld4(&Vs[c][64 + (tx << 2)]);
            float av[4] = {a0, a1, a2, a3};
            float bv[8] = {b0.x, b0.y, b0.z, b0.w, b1.x, b1.y, b1.z, b1.w};
#pragma unroll
            for (int i = 0; i < 4; ++i)
#pragma unroll
                for (int j = 0; j < 8; ++j)
                    acc[i][j] = fmaf(av[i], bv[j], acc[i][j]);
        }
    }
    float* op = opart + (size_t)blockIdx.y * NM;
#pragma unroll
    for (int i = 0; i < 4; ++i) {
        size_t row = rb + (ty << 2) + i;
        float4 o0 = {acc[i][0], acc[i][1], acc[i][2], acc[i][3]};
        float4 o1 = {acc[i][4], acc[i][5], acc[i][6], acc[i][7]};
        *(float4*)&op[row * DHEAD + (tx << 2)] = o0;
        *(float4*)&op[row * DHEAD + 64 + (tx << 2)] = o1;
    }
}

// ---------------------------------------------------------------------------
// K4: reduce the 4 partial O's -> out
// ---------------------------------------------------------------------------
__global__ __launch_bounds__(256) void reduce_kernel(
    const float* __restrict__ opart, float* __restrict__ out) {
    size_t i4 = ((size_t)blockIdx.x * 256 + threadIdx.x) * 4;
    float4 a = ld4(&opart[i4]);
    float4 b = ld4(&opart[(size_t)NM + i4]);
    float4 c = ld4(&opart[2 * (size_t)NM + i4]);
    float4 d = ld4(&opart[3 * (size_t)NM + i4]);
    float4 r;
    r.x = a.x + b.x + c.x + d.x;
    r.y = a.y + b.y + c.y + d.y;
    r.z = a.z + b.z + c.z + d.z;
    r.w = a.w + b.w + c.w + d.w;
    *(float4*)&out[i4] = r;
}

extern "C" void kernel_launch(void* const* d_in, const int* in_sizes, int n_in,
                              void* d_out, int out_size, void* d_ws, size_t ws_size,
                              hipStream_t stream) {
    const float* X  = (const float*)d_in[0];
    const float* Wq = (const float*)d_in[1];
    const float* Wk = (const float*)d_in[2];
    const float* Wv = (const float*)d_in[3];
    float* out  = (float*)d_out;
    float* attn = out + (size_t)N_TOK * DHEAD;
    float* ws = (float*)d_ws;
    // ws layout (floats): Q[NM] K[NM] V[NM] mpart[4N] lpart[4N] mfin[N] lrin[N] Opart[4*NM]
    float* mpart = ws + 3 * (size_t)NM;
    float* lpart = mpart + 4 * N_TOK;
    float* mfin  = lpart + 4 * N_TOK;
    float* lrin  = mfin + N_TOK;
    float* opart = lrin + N_TOK;

    proj_kernel<<<dim3(128, 3), 256, 0, stream>>>(X, Wq, Wk, Wv, ws);
    scores_kernel<<<dim3(128, 4), 256, 0, stream>>>(ws, attn, mpart, lpart);
    merge_kernel<<<32, 256, 0, stream>>>(mpart, lpart, mfin, lrin);
    pv_kernel<<<dim3(128, 4), 256, 0, stream>>>(ws + 2 * (size_t)NM, mfin, lrin,
                                                attn, opart);
    reduce_kernel<<<1024, 256, 0, stream>>>(opart, out);
}

// Round 2
// 363.242 us; speedup vs baseline: 1.8727x; 1.8727x over previous
//
#include <hip/hip_runtime.h>
#include <math.h>

#define N_TOK 8192
#define DMODEL 1024
#define DHEAD 128
#define NM (N_TOK * DHEAD)       // 1048576
#define CS 4                     // column splits for pass1/pass2
#define CCHUNK (N_TOK / CS)      // 2048
#define NIT (CCHUNK / 64)        // 32
#define KS 8                     // K-splits for PV
#define KRANGE (N_TOK / KS)      // 1024
#define NIT2 (KRANGE / 64)       // 16
#define QSCALE 0.08838834764831845f

typedef __bf16 bf16x8 __attribute__((ext_vector_type(8)));
typedef float f32x4 __attribute__((ext_vector_type(4)));
typedef unsigned short u16;
typedef unsigned int u32;

union B8 { uint4 u; bf16x8 b; };

static __device__ __forceinline__ float4 ld4(const float* p) {
    return *(const float4*)p;
}

static __device__ __forceinline__ void gl_lds16(const void* g, void* l) {
    __builtin_amdgcn_global_load_lds(
        (const __attribute__((address_space(1))) u32*)g,
        (__attribute__((address_space(3))) u32*)l, 16, 0, 0);
}

static __device__ __forceinline__ u16 bfbits(float x) {
    return __builtin_bit_cast(u16, (__bf16)x);
}

// ---------------------------------------------------------------------------
// K1: projections  P = X @ W  (fp32, unchanged from R1 — known-good)
// grid (128, 3), block 256. Writes Qf|Kf|Vf contiguous at base pointer.
// ---------------------------------------------------------------------------
__global__ __launch_bounds__(256) void proj_kernel(
    const float* __restrict__ X, const float* __restrict__ Wq,
    const float* __restrict__ Wk, const float* __restrict__ Wv,
    float* __restrict__ base) {
    __shared__ float Xt[32][68];
    __shared__ float Wt[32][132];
    const int tid = threadIdx.x;
    const int tx = tid & 15, ty = tid >> 4;
    const int rb = blockIdx.x * 64;
    const float* W = blockIdx.y == 0 ? Wq : (blockIdx.y == 1 ? Wk : Wv);
    float* P = base + (size_t)blockIdx.y * NM;

    float acc[4][8] = {};
    for (int k0 = 0; k0 < DMODEL; k0 += 32) {
        __syncthreads();
        {
            int r = tid & 63;
            int kq = (tid >> 6) << 2;
#pragma unroll
            for (int h = 0; h < 2; ++h) {
                int kk = kq + 16 * h;
                float4 v = ld4(&X[(size_t)(rb + r) * DMODEL + k0 + kk]);
                Xt[kk + 0][r] = v.x; Xt[kk + 1][r] = v.y;
                Xt[kk + 2][r] = v.z; Xt[kk + 3][r] = v.w;
            }
        }
        {
            int kk = tid >> 3;
            int c4 = (tid & 7) << 2;
#pragma unroll
            for (int p = 0; p < 4; ++p) {
                float4 v = ld4(&W[(size_t)(k0 + kk) * DHEAD + c4 + 32 * p]);
                *(float4*)&Wt[kk][c4 + 32 * p] = v;
            }
        }
        __syncthreads();
#pragma unroll 8
        for (int kk = 0; kk < 32; ++kk) {
            float4 a  = ld4(&Xt[kk][ty << 2]);
            float4 b0 = ld4(&Wt[kk][tx << 2]);
            float4 b1 = ld4(&Wt[kk][64 + (tx << 2)]);
            float av[4] = {a.x, a.y, a.z, a.w};
            float bv[8] = {b0.x, b0.y, b0.z, b0.w, b1.x, b1.y, b1.z, b1.w};
#pragma unroll
            for (int i = 0; i < 4; ++i)
#pragma unroll
                for (int j = 0; j < 8; ++j)
                    acc[i][j] = fmaf(av[i], bv[j], acc[i][j]);
        }
    }
#pragma unroll
    for (int i = 0; i < 4; ++i) {
        size_t row = rb + (ty << 2) + i;
        float4 o0 = {acc[i][0], acc[i][1], acc[i][2], acc[i][3]};
        float4 o1 = {acc[i][4], acc[i][5], acc[i][6], acc[i][7]};
        *(float4*)&P[row * DHEAD + (tx << 2)] = o0;
        *(float4*)&P[row * DHEAD + 64 + (tx << 2)] = o1;
    }
}

// ---------------------------------------------------------------------------
// K1b: split Q (scaled) and K into bf16 hi/lo pairs. grid 512 x 256.
// ---------------------------------------------------------------------------
__global__ __launch_bounds__(256) void split_qk(
    const float* __restrict__ Qf, const float* __restrict__ Kf,
    u16* __restrict__ Qh, u16* __restrict__ Ql,
    u16* __restrict__ Kh, u16* __restrict__ Kl) {
    size_t i0 = ((size_t)blockIdx.x * 256 + threadIdx.x) * 8;
    alignas(16) float v[8];
    alignas(16) u16 h[8];
    alignas(16) u16 l[8];

    *(float4*)&v[0] = ld4(Qf + i0); *(float4*)&v[4] = ld4(Qf + i0 + 4);
#pragma unroll
    for (int j = 0; j < 8; ++j) {
        float x = v[j] * QSCALE;
        __bf16 hb = (__bf16)x;
        h[j] = __builtin_bit_cast(u16, hb);
        l[j] = bfbits(x - (float)hb);
    }
    *(uint4*)(Qh + i0) = *(uint4*)h;
    *(uint4*)(Ql + i0) = *(uint4*)l;

    *(float4*)&v[0] = ld4(Kf + i0); *(float4*)&v[4] = ld4(Kf + i0 + 4);
#pragma unroll
    for (int j = 0; j < 8; ++j) {
        float x = v[j];
        __bf16 hb = (__bf16)x;
        h[j] = __builtin_bit_cast(u16, hb);
        l[j] = bfbits(x - (float)hb);
    }
    *(uint4*)(Kh + i0) = *(uint4*)h;
    *(uint4*)(Kl + i0) = *(uint4*)l;
}

// ---------------------------------------------------------------------------
// K1c: V fp32 [8192][128] -> Vt bf16 [128][8192]. grid 128 x 256.
// ---------------------------------------------------------------------------
__global__ __launch_bounds__(256) void vt_kernel(
    const float* __restrict__ Vf, u16* __restrict__ Vt) {
    __shared__ float t[64][129];
    const int tb = blockIdx.x * 64;
    const int tid = threadIdx.x;
    const int tok = tid >> 2, dq = (tid & 3) * 32;
#pragma unroll
    for (int h = 0; h < 8; ++h) {
        float4 v = ld4(&Vf[(size_t)(tb + tok) * DHEAD + dq + h * 4]);
        t[tok][dq + h * 4 + 0] = v.x;
        t[tok][dq + h * 4 + 1] = v.y;
        t[tok][dq + h * 4 + 2] = v.z;
        t[tok][dq + h * 4 + 3] = v.w;
    }
    __syncthreads();
    const int tl = tid & 63, dg = tid >> 6;
#pragma unroll
    for (int dd = 0; dd < 32; ++dd) {
        int d = dg * 32 + dd;
        Vt[(size_t)d * N_TOK + tb + tl] = bfbits(t[tl][d]);
    }
}

// ---------------------------------------------------------------------------
// K2/K3: attention core. PASS=1: online (m,l) only. PASS=2: write P fp32.
// S^T = K·Q^T via bf16x3 MFMA (KhQh + KhQl + KlQh). Q-frags resident in
// registers; K tiles double-buffered in LDS via global_load_lds with
// source-side XOR swizzle (bank-conflict-free ds_read_b128).
// grid (128 row-blocks, CS col-splits), block 256 = 4 waves.
// Block: 64 rows (r) x 2048 cols (c); per iter 64 c, each wave 16 c.
// ---------------------------------------------------------------------------
template <int PASS>
__global__ __launch_bounds__(256, 2) void attn_core(
    const u16* __restrict__ Qh, const u16* __restrict__ Ql,
    const u16* __restrict__ Kh, const u16* __restrict__ Kl,
    float* __restrict__ mpart, float* __restrict__ lpart,
    const float* __restrict__ mfin, const float* __restrict__ linv,
    float* __restrict__ attn) {
    __shared__ uint4 Kt[2][2][1024];   // [buf][hi/lo][c*16 + swizzled granule]
    __shared__ float msc[2][4][64];    // merge scratch [m/l][wave][r]
    const int tid = threadIdx.x;
    const int lane = tid & 63, wv = tid >> 6;
    const int l15 = lane & 15, lg = lane >> 4;
    const int rb = blockIdx.x * 64;
    const int cb0 = blockIdx.y * CCHUNK;

    // Resident Q B-fragments: [hi/lo][nt(r-tile)][kd(d-chunk)]
    B8 qf[2][4][4];
#pragma unroll
    for (int nt = 0; nt < 4; ++nt) {
        int r = rb + nt * 16 + l15;
#pragma unroll
        for (int kd = 0; kd < 4; ++kd) {
            size_t off = (size_t)r * DHEAD + kd * 32 + lg * 8;
            qf[0][nt][kd].u = *(const uint4*)(Qh + off);
            qf[1][nt][kd].u = *(const uint4*)(Ql + off);
        }
    }

    float m[4], l[4], mreg[4], rinv[4];
#pragma unroll
    for (int nt = 0; nt < 4; ++nt) { m[nt] = -INFINITY; l[nt] = 0.f; }
    if constexpr (PASS == 2) {
#pragma unroll
        for (int nt = 0; nt < 4; ++nt) {
            int r = rb + nt * 16 + l15;
            mreg[nt] = mfin[r];
            rinv[nt] = linv[r];
        }
    }

    auto stage = [&](int buf, int it) {
        int cb = cb0 + it * 64;
#pragma unroll
        for (int i = 0; i < 4; ++i) {
            int g = i * 256 + wv * 64 + lane;   // granule 0..1023
            int c = g >> 4;
            int gs = g & 15;
            int gd = gs ^ (c & 7);              // inverse swizzle on source
            size_t soff = (size_t)(cb + c) * DHEAD + gd * 8;
            gl_lds16(Kh + soff, &Kt[buf][0][i * 256 + wv * 64]);
            gl_lds16(Kl + soff, &Kt[buf][1][i * 256 + wv * 64]);
        }
    };

    stage(0, 0);
    __syncthreads();
    int cur = 0;
    const int cl = wv * 16 + l15;   // A-fragment row (c within tile)
    for (int it = 0; it < NIT; ++it) {
        if (it + 1 < NIT) stage(cur ^ 1, it + 1);
        f32x4 acc[4];
#pragma unroll
        for (int nt = 0; nt < 4; ++nt) acc[nt] = (f32x4){0.f, 0.f, 0.f, 0.f};
#pragma unroll
        for (int kd = 0; kd < 4; ++kd) {
            B8 ahh, alo;
            int gs = (kd * 4 + lg) ^ (cl & 7);
            ahh.u = Kt[cur][0][cl * 16 + gs];
            alo.u = Kt[cur][1][cl * 16 + gs];
#pragma unroll
            for (int nt = 0; nt < 4; ++nt)
                acc[nt] = __builtin_amdgcn_mfma_f32_16x16x32_bf16(
                    ahh.b, qf[0][nt][kd].b, acc[nt], 0, 0, 0);
#pragma unroll
            for (int nt = 0; nt < 4; ++nt)
                acc[nt] = __builtin_amdgcn_mfma_f32_16x16x32_bf16(
                    ahh.b, qf[1][nt][kd].b, acc[nt], 0, 0, 0);
#pragma unroll
            for (int nt = 0; nt < 4; ++nt)
                acc[nt] = __builtin_amdgcn_mfma_f32_16x16x32_bf16(
                    alo.b, qf[0][nt][kd].b, acc[nt], 0, 0, 0);
        }
        if constexpr (PASS == 1) {
#pragma unroll
            for (int nt = 0; nt < 4; ++nt) {
                float v0 = acc[nt][0], v1 = acc[nt][1];
                float v2 = acc[nt][2], v3 = acc[nt][3];
                float tm = fmaxf(fmaxf(v0, v1), fmaxf(v2, v3));
                float mn = fmaxf(m[nt], tm);
                float s_ = __expf(v0 - mn) + __expf(v1 - mn) +
                           __expf(v2 - mn) + __expf(v3 - mn);
                l[nt] = l[nt] * __expf(m[nt] - mn) + s_;
                m[nt] = mn;
            }
        } else {
            int c0 = cb0 + it * 64 + wv * 16 + lg * 4;
#pragma unroll
            for (int nt = 0; nt < 4; ++nt) {
                float4 p;
                p.x = __expf(acc[nt][0] - mreg[nt]) * rinv[nt];
                p.y = __expf(acc[nt][1] - mreg[nt]) * rinv[nt];
                p.z = __expf(acc[nt][2] - mreg[nt]) * rinv[nt];
                p.w = __expf(acc[nt][3] - mreg[nt]) * rinv[nt];
                size_t row = rb + nt * 16 + l15;
                *(float4*)&attn[row * (size_t)N_TOK + c0] = p;
            }
        }
        __syncthreads();
        cur ^= 1;
    }

    if constexpr (PASS == 1) {
        // merge across the 4 lane-groups (each saw a different c-subset)
#pragma unroll
        for (int nt = 0; nt < 4; ++nt) {
            float mm = m[nt], ll = l[nt];
#pragma unroll
            for (int off = 16; off < 64; off <<= 1) {
                float mo = __shfl_xor(mm, off);
                float lo_ = __shfl_xor(ll, off);
                float mx = fmaxf(mm, mo);
                ll = ll * __expf(mm - mx) + lo_ * __expf(mo - mx);
                mm = mx;
            }
            m[nt] = mm; l[nt] = ll;
        }
        if (lane < 16) {
#pragma unroll
            for (int nt = 0; nt < 4; ++nt) {
                msc[0][wv][nt * 16 + lane] = m[nt];
                msc[1][wv][nt * 16 + lane] = l[nt];
            }
        }
        __syncthreads();
        if (tid < 64) {
            float mm = msc[0][0][tid], ll = msc[1][0][tid];
#pragma unroll
            for (int w = 1; w < 4; ++w) {
                float mo = msc[0][w][tid], lo_ = msc[1][w][tid];
                float mx = fmaxf(mm, mo);
                ll = ll * __expf(mm - mx) + lo_ * __expf(mo - mx);
                mm = mx;
            }
            mpart[blockIdx.y * N_TOK + rb + tid] = mm;
            lpart[blockIdx.y * N_TOK + rb + tid] = ll;
        }
    }
}

// ---------------------------------------------------------------------------
// K2b: merge CS column-split (m,l) partials -> m_final, 1/l
// ---------------------------------------------------------------------------
__global__ __launch_bounds__(256) void merge_kernel(
    const float* __restrict__ mpart, const float* __restrict__ lpart,
    float* __restrict__ mfin, float* __restrict__ linv) {
    int row = blockIdx.x * 256 + threadIdx.x;
    float m = mpart[row];
#pragma unroll
    for (int c = 1; c < CS; ++c) m = fmaxf(m, mpart[c * N_TOK + row]);
    float l = 0.f;
#pragma unroll
    for (int c = 0; c < CS; ++c)
        l += lpart[c * N_TOK + row] * __expf(mpart[c * N_TOK + row] - m);
    mfin[row] = m;
    linv[row] = 1.0f / l;
}

// ---------------------------------------------------------------------------
// K4: O = P @ V via bf16 MFMA. A = attn fp32 (reg-staged -> bf16 LDS, T14
// issue-early/write-late), B = Vt via global_load_lds (swizzled source).
// grid (64 M-blocks, KS k-splits), block 256 = 4 waves (each 32 r x 128 d).
// Partials accumulated with atomicAdd into memset out.
// ---------------------------------------------------------------------------
__global__ __launch_bounds__(256, 2) void pv_kernel(
    const float* __restrict__ attn, const u16* __restrict__ Vt,
    float* __restrict__ out) {
    __shared__ uint4 Pt[2][1024];    // [buf][r*8 + swizzled granule], 128r x 64c
    __shared__ uint4 Vts[2][1024];   // [buf][d*8 + swizzled granule], 128d x 64c
    const int tid = threadIdx.x, lane = tid & 63, wv = tid >> 6;
    const int l15 = lane & 15, lg = lane >> 4;
    const int rb = blockIdx.x * 128;
    const int cb0 = blockIdx.y * KRANGE;
    const int ar = tid >> 1, ah_ = tid & 1;   // A-staging: row, col-half

    f32x4 acc[2][8];
#pragma unroll
    for (int mt = 0; mt < 2; ++mt)
#pragma unroll
        for (int nt = 0; nt < 8; ++nt) acc[mt][nt] = (f32x4){0.f, 0.f, 0.f, 0.f};

    float4 av[8];
    auto loadA = [&](int it) {
        const float* src = attn + (size_t)(rb + ar) * N_TOK + cb0 + it * 64 + ah_ * 32;
#pragma unroll
        for (int k = 0; k < 8; ++k) av[k] = ld4(src + k * 4);
    };
    auto writeA = [&](int buf) {
#pragma unroll
        for (int k = 0; k < 4; ++k) {
            alignas(16) u16 h[8];
            float4 x = av[2 * k], y = av[2 * k + 1];
            h[0] = bfbits(x.x); h[1] = bfbits(x.y);
            h[2] = bfbits(x.z); h[3] = bfbits(x.w);
            h[4] = bfbits(y.x); h[5] = bfbits(y.y);
            h[6] = bfbits(y.z); h[7] = bfbits(y.w);
            int gs = (ah_ * 4 + k) ^ (ar & 7);
            Pt[buf][ar * 8 + gs] = *(uint4*)h;
        }
    };
    auto stageB = [&](int buf, int it) {
        int cb = cb0 + it * 64;
#pragma unroll
        for (int i = 0; i < 4; ++i) {
            int g = i * 256 + wv * 64 + lane;
            int d = g >> 3, gs = g & 7, gd = gs ^ (d & 7);
            gl_lds16(Vt + (size_t)d * N_TOK + cb + gd * 8,
                     &Vts[buf][i * 256 + wv * 64]);
        }
    };

    stageB(0, 0);
    loadA(0);
    writeA(0);
    __syncthreads();
    int cur = 0;
    for (int it = 0; it < NIT2; ++it) {
        const bool more = (it + 1 < NIT2);
        if (more) { stageB(cur ^ 1, it + 1); loadA(it + 1); }
#pragma unroll
        for (int kc = 0; kc < 2; ++kc) {
            B8 a0, a1, bb[8];
            int r0 = wv * 32 + l15;
            int r1 = r0 + 16;
            a0.u = Pt[cur][r0 * 8 + ((kc * 4 + lg) ^ (r0 & 7))];
            a1.u = Pt[cur][r1 * 8 + ((kc * 4 + lg) ^ (r1 & 7))];
#pragma unroll
            for (int nt = 0; nt < 8; ++nt) {
                int d = nt * 16 + l15;
                bb[nt].u = Vts[cur][d * 8 + ((kc * 4 + lg) ^ (d & 7))];
            }
#pragma unroll
            for (int nt = 0; nt < 8; ++nt) {
                acc[0][nt] = __builtin_amdgcn_mfma_f32_16x16x32_bf16(
                    a0.b, bb[nt].b, acc[0][nt], 0, 0, 0);
                acc[1][nt] = __builtin_amdgcn_mfma_f32_16x16x32_bf16(
                    a1.b, bb[nt].b, acc[1][nt], 0, 0, 0);
            }
        }
        if (more) writeA(cur ^ 1);
        __syncthreads();
        cur ^= 1;
    }
#pragma unroll
    for (int mt = 0; mt < 2; ++mt) {
        int r0 = rb + wv * 32 + mt * 16 + lg * 4;
#pragma unroll
        for (int nt = 0; nt < 8; ++nt) {
            int d = nt * 16 + l15;
#pragma unroll
            for (int q = 0; q < 4; ++q)
                atomicAdd(&out[(size_t)(r0 + q) * DHEAD + d], acc[mt][nt][q]);
        }
    }
}

extern "C" void kernel_launch(void* const* d_in, const int* in_sizes, int n_in,
                              void* d_out, int out_size, void* d_ws, size_t ws_size,
                              hipStream_t stream) {
    const float* X  = (const float*)d_in[0];
    const float* Wq = (const float*)d_in[1];
    const float* Wk = (const float*)d_in[2];
    const float* Wv = (const float*)d_in[3];
    float* out  = (float*)d_out;
    float* attn = out + (size_t)NM;
    float* ws = (float*)d_ws;

    // ws layout (floats), total ~5.63*NM = 23.6 MB:
    u16*  Vt    = (u16*)ws;                       // NM shorts = NM/2 floats
    float* mpart = ws + NM / 2;                   // CS*N
    float* lpart = mpart + CS * N_TOK;            // CS*N
    float* mfin  = lpart + CS * N_TOK;            // N
    float* linv  = mfin + N_TOK;                  // N
    float* spl   = ws + NM / 2 + 16 * N_TOK;      // splits base (slack-padded)
    u16* Qh = (u16*)spl;                          // NM shorts each
    u16* Ql = Qh + NM;
    u16* Kh = Ql + NM;
    u16* Kl = Kh + NM;
    float* Qf = spl + 2 * (size_t)NM;             // fp32 proj outputs
    float* Kf = Qf + NM;
    float* Vf = Kf + NM;

    proj_kernel<<<dim3(128, 3), 256, 0, stream>>>(X, Wq, Wk, Wv, Qf);
    split_qk<<<dim3(NM / 2048), 256, 0, stream>>>(Qf, Kf, Qh, Ql, Kh, Kl);
    vt_kernel<<<dim3(128), 256, 0, stream>>>(Vf, Vt);
    attn_core<1><<<dim3(128, CS), 256, 0, stream>>>(Qh, Ql, Kh, Kl, mpart, lpart,
                                                    nullptr, nullptr, nullptr);
    merge_kernel<<<dim3(32), 256, 0, stream>>>(mpart, lpart, mfin, linv);
    attn_core<2><<<dim3(128, CS), 256, 0, stream>>>(Qh, Ql, Kh, Kl, nullptr, nullptr,
                                                    mfin, linv, attn);
    hipMemsetAsync(out, 0, (size_t)NM * sizeof(float), stream);
    pv_kernel<<<dim3(64, KS), 256, 0, stream>>>(attn, Vt, out);
}

// Round 3
// 340.627 us; speedup vs baseline: 1.9970x; 1.0664x over previous
//
#include <hip/hip_runtime.h>
#include <math.h>

#define N_TOK 8192
#define DMODEL 1024
#define DHEAD 128
#define NM (N_TOK * DHEAD)       // 1048576
#define CS 4                     // column splits for attention passes
#define CCHUNK (N_TOK / CS)      // 2048
#define NIT (CCHUNK / 64)        // 32
#define QSCALE 0.08838834764831845f

typedef __bf16 bf16x8 __attribute__((ext_vector_type(8)));
typedef float f32x4 __attribute__((ext_vector_type(4)));
typedef unsigned short u16;
typedef unsigned int u32;

union B8 { uint4 u; bf16x8 b; };

static __device__ __forceinline__ float4 ld4(const float* p) {
    return *(const float4*)p;
}

static __device__ __forceinline__ void gl_lds16(const void* g, void* l) {
    __builtin_amdgcn_global_load_lds(
        (const __attribute__((address_space(1))) u32*)g,
        (__attribute__((address_space(3))) u32*)l, 16, 0, 0);
}

static __device__ __forceinline__ u16 bfbits(float x) {
    return __builtin_bit_cast(u16, (__bf16)x);
}
static __device__ __forceinline__ u16 b2u(__bf16 h) {
    return __builtin_bit_cast(u16, h);
}

// ---------------------------------------------------------------------------
// K0a: split X fp32 -> Xh, Xl bf16. 8M elements, grid 4096 x 256.
// ---------------------------------------------------------------------------
__global__ __launch_bounds__(256) void split_x(
    const float* __restrict__ X, u16* __restrict__ Xh, u16* __restrict__ Xl) {
    size_t i0 = ((size_t)blockIdx.x * 256 + threadIdx.x) * 8;
    alignas(16) float v[8];
    alignas(16) u16 h[8];
    alignas(16) u16 l[8];
    *(float4*)&v[0] = ld4(X + i0); *(float4*)&v[4] = ld4(X + i0 + 4);
#pragma unroll
    for (int j = 0; j < 8; ++j) {
        __bf16 hb = (__bf16)v[j];
        h[j] = b2u(hb);
        l[j] = bfbits(v[j] - (float)hb);
    }
    *(uint4*)(Xh + i0) = *(uint4*)h;
    *(uint4*)(Xl + i0) = *(uint4*)l;
}

// ---------------------------------------------------------------------------
// K0b: W [1024][128] x3 -> Wt hi/lo [384][1024] (transposed, concat Q|K|V).
// ---------------------------------------------------------------------------
__global__ __launch_bounds__(256) void splitw(
    const float* __restrict__ Wq, const float* __restrict__ Wk,
    const float* __restrict__ Wv, u16* __restrict__ Wth, u16* __restrict__ Wtl) {
    size_t o = (size_t)blockIdx.x * 256 + threadIdx.x;   // 0..393215
    int k = o & 1023, cg = o >> 10;                      // cg 0..383
    int w = cg >> 7, c = cg & 127;
    const float* W = w == 0 ? Wq : (w == 1 ? Wk : Wv);
    float x = W[(size_t)k * 128 + c];
    __bf16 hb = (__bf16)x;
    Wth[o] = b2u(hb);
    Wtl[o] = bfbits(x - (float)hb);
}

// ---------------------------------------------------------------------------
// K1: projections via bf16x3 MFMA, swapped operands.
// A = W^T (m=c, from L2-resident global), B = X rows (n=r, LDS dbuf).
// D = C^T fragments. Epilogue splits directly into Qh/Ql (scaled), Kh/Kl,
// and V^T bf16 (Vt) — no fp32 intermediates.
// grid (256 row-blocks of 32, 2 c-halves of 192), block 256 = 4 waves.
// Wave: 16 r x 96 c (6 m-tiles).
// ---------------------------------------------------------------------------
__global__ __launch_bounds__(256) void proj_mfma(
    const u16* __restrict__ Xh, const u16* __restrict__ Xl,
    const u16* __restrict__ Wth, const u16* __restrict__ Wtl,
    u16* __restrict__ Qh, u16* __restrict__ Ql,
    u16* __restrict__ Kh, u16* __restrict__ Kl, u16* __restrict__ Vt) {
    __shared__ uint4 Xs[2][2][128];   // [buf][hi/lo][r*4 + swizzled granule]
    const int tid = threadIdx.x, lane = tid & 63, wv = tid >> 6;
    const int l15 = lane & 15, lg = lane >> 4;
    const int rb = blockIdx.x * 32;
    const int ch = blockIdx.y;        // c-base = ch*192
    const int rt = wv & 1;            // r-tile (16 rows)
    const int cq = wv >> 1;           // c-quarter (96 cols)

    f32x4 acc[6];
#pragma unroll
    for (int mt = 0; mt < 6; ++mt) acc[mt] = (f32x4){0.f, 0.f, 0.f, 0.f};

    auto stage = [&](int buf, int k0) {
        // wave w stages 64 granules: waves 0,1 -> hi, 2,3 -> lo
        int split = wv >> 1;
        int idx = (wv & 1) * 64 + lane;     // granule 0..127 within split
        int r = idx >> 2, gs = idx & 3, gd = gs ^ (r & 3);
        const u16* src = (split ? Xl : Xh) +
                         (size_t)(rb + r) * DMODEL + k0 + gd * 8;
        gl_lds16(src, &Xs[buf][split][(wv & 1) * 64]);
    };

    stage(0, 0);
    __syncthreads();
    int cur = 0;
    for (int ks = 0; ks < 32; ++ks) {
        if (ks + 1 < 32) stage(cur ^ 1, (ks + 1) * 32);
        B8 bh, bl;
        {
            int r = rt * 16 + l15;
            bh.u = Xs[cur][0][r * 4 + (lg ^ (r & 3))];
            bl.u = Xs[cur][1][r * 4 + (lg ^ (r & 3))];
        }
#pragma unroll
        for (int mt = 0; mt < 6; ++mt) {
            int c = ch * 192 + cq * 96 + mt * 16 + l15;
            size_t off = (size_t)c * DMODEL + ks * 32 + lg * 8;
            B8 ah, al;
            ah.u = *(const uint4*)(Wth + off);
            al.u = *(const uint4*)(Wtl + off);
            acc[mt] = __builtin_amdgcn_mfma_f32_16x16x32_bf16(
                ah.b, bh.b, acc[mt], 0, 0, 0);
            acc[mt] = __builtin_amdgcn_mfma_f32_16x16x32_bf16(
                ah.b, bl.b, acc[mt], 0, 0, 0);
            acc[mt] = __builtin_amdgcn_mfma_f32_16x16x32_bf16(
                al.b, bh.b, acc[mt], 0, 0, 0);
        }
        __syncthreads();
        cur ^= 1;
    }

    // Epilogue: lane holds D[c][r]: r = rb + rt*16 + l15 (fixed),
    // c = ch*192 + cq*96 + mt*16 + lg*4 + q. Tile class uniform per mt.
    const int r = rb + rt * 16 + l15;
#pragma unroll
    for (int mt = 0; mt < 6; ++mt) {
        int ctile = ch * 192 + cq * 96 + mt * 16;   // multiple of 16, uniform
#pragma unroll
        for (int q = 0; q < 4; ++q) {
            int c = ctile + lg * 4 + q;
            float x = acc[mt][q];
            if (ctile < 128) {          // Q (scaled)
                float v = x * QSCALE;
                __bf16 hb = (__bf16)v;
                Qh[(size_t)r * DHEAD + c] = b2u(hb);
                Ql[(size_t)r * DHEAD + c] = bfbits(v - (float)hb);
            } else if (ctile < 256) {   // K
                __bf16 hb = (__bf16)x;
                Kh[(size_t)r * DHEAD + (c - 128)] = b2u(hb);
                Kl[(size_t)r * DHEAD + (c - 128)] = bfbits(x - (float)hb);
            } else {                    // V -> transposed bf16
                Vt[(size_t)(c - 256) * N_TOK + r] = bfbits(x);
            }
        }
    }
}

// ---------------------------------------------------------------------------
// K1d: fast zero of out (replaces pathologically slow hipMemsetAsync fill).
// ---------------------------------------------------------------------------
__global__ __launch_bounds__(256) void zero_out(float* __restrict__ out) {
    size_t i = ((size_t)blockIdx.x * 256 + threadIdx.x) * 4;
    *(float4*)(out + i) = (float4){0.f, 0.f, 0.f, 0.f};
}

// ---------------------------------------------------------------------------
// K2/K3: attention core. PASS=1: online (m,l) only.
// PASS=2: write normalized P fp32 to attn AND accumulate O = P·V fused
// (P-tile via swizzled LDS round-trip; V B-frags from L2-resident Vt;
// O partials atomicAdd into zeroed out).
// grid (128 row-blocks, CS col-splits), block 256 = 4 waves.
// ---------------------------------------------------------------------------
template <int PASS>
__global__ __launch_bounds__(256, 2) void attn_core(
    const u16* __restrict__ Qh, const u16* __restrict__ Ql,
    const u16* __restrict__ Kh, const u16* __restrict__ Kl,
    float* __restrict__ mpart, float* __restrict__ lpart,
    const float* __restrict__ mfin, const float* __restrict__ linv,
    float* __restrict__ attn, const u16* __restrict__ Vt,
    float* __restrict__ outp) {
    __shared__ uint4 Kt[2][2][1024];   // [buf][hi/lo][c*16 + swizzled granule]
    __shared__ uint4 Pt[512];          // P tile 64r x 64c bf16, swizzled
    __shared__ float msc[2][4][64];    // merge scratch
    const int tid = threadIdx.x;
    const int lane = tid & 63, wv = tid >> 6;
    const int l15 = lane & 15, lg = lane >> 4;
    const int rb = blockIdx.x * 64;
    const int cb0 = blockIdx.y * CCHUNK;

    // Resident Q B-fragments: [hi/lo][nt(r-tile)][kd(d-chunk)]
    B8 qf[2][4][4];
#pragma unroll
    for (int nt = 0; nt < 4; ++nt) {
        int r = rb + nt * 16 + l15;
#pragma unroll
        for (int kd = 0; kd < 4; ++kd) {
            size_t off = (size_t)r * DHEAD + kd * 32 + lg * 8;
            qf[0][nt][kd].u = *(const uint4*)(Qh + off);
            qf[1][nt][kd].u = *(const uint4*)(Ql + off);
        }
    }

    float m[4], l[4], mreg[4], rinv[4];
#pragma unroll
    for (int nt = 0; nt < 4; ++nt) { m[nt] = -INFINITY; l[nt] = 0.f; }
    f32x4 accO[8];
    if constexpr (PASS == 2) {
#pragma unroll
        for (int nt = 0; nt < 4; ++nt) {
            int r = rb + nt * 16 + l15;
            mreg[nt] = mfin[r];
            rinv[nt] = linv[r];
        }
#pragma unroll
        for (int nt = 0; nt < 8; ++nt) accO[nt] = (f32x4){0.f, 0.f, 0.f, 0.f};
    }

    auto stage = [&](int buf, int it) {
        int cb = cb0 + it * 64;
#pragma unroll
        for (int i = 0; i < 4; ++i) {
            int g = i * 256 + wv * 64 + lane;   // granule 0..1023
            int c = g >> 4;
            int gs = g & 15;
            int gd = gs ^ (c & 7);              // inverse swizzle on source
            size_t soff = (size_t)(cb + c) * DHEAD + gd * 8;
            gl_lds16(Kh + soff, &Kt[buf][0][i * 256 + wv * 64]);
            gl_lds16(Kl + soff, &Kt[buf][1][i * 256 + wv * 64]);
        }
    };

    stage(0, 0);
    __syncthreads();
    int cur = 0;
    const int cl = wv * 16 + l15;   // A-fragment row (c within tile)
    for (int it = 0; it < NIT; ++it) {
        if (it + 1 < NIT) stage(cur ^ 1, it + 1);
        f32x4 acc[4];
#pragma unroll
        for (int nt = 0; nt < 4; ++nt) acc[nt] = (f32x4){0.f, 0.f, 0.f, 0.f};
#pragma unroll
        for (int kd = 0; kd < 4; ++kd) {
            B8 ahh, alo;
            int gs = (kd * 4 + lg) ^ (cl & 7);
            ahh.u = Kt[cur][0][cl * 16 + gs];
            alo.u = Kt[cur][1][cl * 16 + gs];
#pragma unroll
            for (int nt = 0; nt < 4; ++nt)
                acc[nt] = __builtin_amdgcn_mfma_f32_16x16x32_bf16(
                    ahh.b, qf[0][nt][kd].b, acc[nt], 0, 0, 0);
#pragma unroll
            for (int nt = 0; nt < 4; ++nt)
                acc[nt] = __builtin_amdgcn_mfma_f32_16x16x32_bf16(
                    ahh.b, qf[1][nt][kd].b, acc[nt], 0, 0, 0);
#pragma unroll
            for (int nt = 0; nt < 4; ++nt)
                acc[nt] = __builtin_amdgcn_mfma_f32_16x16x32_bf16(
                    alo.b, qf[0][nt][kd].b, acc[nt], 0, 0, 0);
        }
        if constexpr (PASS == 1) {
#pragma unroll
            for (int nt = 0; nt < 4; ++nt) {
                float v0 = acc[nt][0], v1 = acc[nt][1];
                float v2 = acc[nt][2], v3 = acc[nt][3];
                float tm = fmaxf(fmaxf(v0, v1), fmaxf(v2, v3));
                float mn = fmaxf(m[nt], tm);
                float s_ = __expf(v0 - mn) + __expf(v1 - mn) +
                           __expf(v2 - mn) + __expf(v3 - mn);
                l[nt] = l[nt] * __expf(m[nt] - mn) + s_;
                m[nt] = mn;
            }
            __syncthreads();
        } else {
            // normalized P: write fp32 to attn + bf16 to Pt (swizzled)
            int c0 = cb0 + it * 64 + wv * 16 + lg * 4;
            int gq = ((wv * 2 + (lg >> 1)) << 1) | (lg & 1);  // pre-swz half-granule
#pragma unroll
            for (int nt = 0; nt < 4; ++nt) {
                float4 p;
                p.x = __expf(acc[nt][0] - mreg[nt]) * rinv[nt];
                p.y = __expf(acc[nt][1] - mreg[nt]) * rinv[nt];
                p.z = __expf(acc[nt][2] - mreg[nt]) * rinv[nt];
                p.w = __expf(acc[nt][3] - mreg[nt]) * rinv[nt];
                int rl = nt * 16 + l15;
                *(float4*)&attn[(size_t)(rb + rl) * N_TOK + c0] = p;
                ushort4 pb;
                pb.x = bfbits(p.x); pb.y = bfbits(p.y);
                pb.z = bfbits(p.z); pb.w = bfbits(p.w);
                int hg = (((wv * 2 + (lg >> 1)) ^ (rl & 7)) << 1) | (lg & 1);
                ((ushort4*)Pt)[rl * 16 + hg] = pb;
            }
            (void)gq;
            __syncthreads();   // Pt visible (+ Kt[cur^1] staged drain)
            // PV: O[16r x 128d] per wave; A from Pt, B from L2-resident Vt
            int cbv = cb0 + it * 64;
            int ra = wv * 16 + l15;
#pragma unroll
            for (int kc = 0; kc < 2; ++kc) {
                B8 a;
                a.u = Pt[ra * 8 + ((kc * 4 + lg) ^ (ra & 7))];
#pragma unroll
                for (int dt = 0; dt < 8; ++dt) {
                    B8 b;
                    b.u = *(const uint4*)(Vt + (size_t)(dt * 16 + l15) * N_TOK +
                                          cbv + kc * 32 + lg * 8);
                    accO[dt] = __builtin_amdgcn_mfma_f32_16x16x32_bf16(
                        a.b, b.b, accO[dt], 0, 0, 0);
                }
            }
            __syncthreads();   // protect Pt before next iter overwrite
        }
        cur ^= 1;
    }

    if constexpr (PASS == 1) {
#pragma unroll
        for (int nt = 0; nt < 4; ++nt) {
            float mm = m[nt], ll = l[nt];
#pragma unroll
            for (int off = 16; off < 64; off <<= 1) {
                float mo = __shfl_xor(mm, off);
                float lo_ = __shfl_xor(ll, off);
                float mx = fmaxf(mm, mo);
                ll = ll * __expf(mm - mx) + lo_ * __expf(mo - mx);
                mm = mx;
            }
            m[nt] = mm; l[nt] = ll;
        }
        if (lane < 16) {
#pragma unroll
            for (int nt = 0; nt < 4; ++nt) {
                msc[0][wv][nt * 16 + lane] = m[nt];
                msc[1][wv][nt * 16 + lane] = l[nt];
            }
        }
        __syncthreads();
        if (tid < 64) {
            float mm = msc[0][0][tid], ll = msc[1][0][tid];
#pragma unroll
            for (int w = 1; w < 4; ++w) {
                float mo = msc[0][w][tid], lo_ = msc[1][w][tid];
                float mx = fmaxf(mm, mo);
                ll = ll * __expf(mm - mx) + lo_ * __expf(mo - mx);
                mm = mx;
            }
            mpart[blockIdx.y * N_TOK + rb + tid] = mm;
            lpart[blockIdx.y * N_TOK + rb + tid] = ll;
        }
    } else {
        // O partial epilogue: lane holds D[r][d]: r = wv*16 + lg*4+q, d = dt*16+l15
#pragma unroll
        for (int dt = 0; dt < 8; ++dt) {
            int d = dt * 16 + l15;
            int r0 = rb + wv * 16 + lg * 4;
#pragma unroll
            for (int q = 0; q < 4; ++q)
                atomicAdd(&outp[(size_t)(r0 + q) * DHEAD + d], accO[dt][q]);
        }
    }
}

// ---------------------------------------------------------------------------
// K2b: merge CS column-split (m,l) partials -> m_final, 1/l
// ---------------------------------------------------------------------------
__global__ __launch_bounds__(256) void merge_kernel(
    const float* __restrict__ mpart, const float* __restrict__ lpart,
    float* __restrict__ mfin, float* __restrict__ linv) {
    int row = blockIdx.x * 256 + threadIdx.x;
    float m = mpart[row];
#pragma unroll
    for (int c = 1; c < CS; ++c) m = fmaxf(m, mpart[c * N_TOK + row]);
    float l = 0.f;
#pragma unroll
    for (int c = 0; c < CS; ++c)
        l += lpart[c * N_TOK + row] * __expf(mpart[c * N_TOK + row] - m);
    mfin[row] = m;
    linv[row] = 1.0f / l;
}

extern "C" void kernel_launch(void* const* d_in, const int* in_sizes, int n_in,
                              void* d_out, int out_size, void* d_ws, size_t ws_size,
                              hipStream_t stream) {
    const float* X  = (const float*)d_in[0];
    const float* Wq = (const float*)d_in[1];
    const float* Wk = (const float*)d_in[2];
    const float* Wv = (const float*)d_in[3];
    float* out  = (float*)d_out;
    float* attn = out + (size_t)NM;
    float* ws = (float*)d_ws;

    // ws layout (floats), total ~11.5M floats = 46 MB:
    u16*  Vt    = (u16*)ws;                       // NM shorts
    float* mpart = ws + NM / 2;                   // CS*N
    float* lpart = mpart + CS * N_TOK;
    float* mfin  = lpart + CS * N_TOK;
    float* linv  = mfin + N_TOK;
    float* spl   = ws + NM / 2 + 16 * N_TOK;
    u16* Qh = (u16*)spl;                          // NM shorts each
    u16* Ql = Qh + NM;
    u16* Kh = Ql + NM;
    u16* Kl = Kh + NM;
    u16* Xh = Kl + NM;                            // 8M shorts each
    u16* Xl = Xh + (size_t)N_TOK * DMODEL;
    u16* Wth = Xl + (size_t)N_TOK * DMODEL;       // 384*1024 shorts each
    u16* Wtl = Wth + 384 * DMODEL;

    split_x<<<dim3(4096), 256, 0, stream>>>(X, Xh, Xl);
    splitw<<<dim3(1536), 256, 0, stream>>>(Wq, Wk, Wv, Wth, Wtl);
    proj_mfma<<<dim3(256, 2), 256, 0, stream>>>(Xh, Xl, Wth, Wtl,
                                                Qh, Ql, Kh, Kl, Vt);
    zero_out<<<dim3(1024), 256, 0, stream>>>(out);
    attn_core<1><<<dim3(128, CS), 256, 0, stream>>>(
        Qh, Ql, Kh, Kl, mpart, lpart, nullptr, nullptr, nullptr, nullptr, nullptr);
    merge_kernel<<<dim3(32), 256, 0, stream>>>(mpart, lpart, mfin, linv);
    attn_core<2><<<dim3(128, CS), 256, 0, stream>>>(
        Qh, Ql, Kh, Kl, nullptr, nullptr, mfin, linv, attn, Vt, out);
}